// Round 4
// baseline (55.558 us; speedup 1.0000x reference)
//
#include <hip/hip_runtime.h>

// SIR RK4, B=65536 systems, 200 time points, out (B,200,3) f32 = 157.3 MB.
// Round 4: minimize L2 partial-line RMW. Two 100-point chunks per system ->
// 1200 B contiguous runs per row per flush (vs 480 B): first-touch partial
// lines drop from ~5/row to ~2/row. 64 systems/block (1 wave, barrier-free),
// LDS 78.8 KB -> 2 blocks/CU so flush drains overlap the other block's
// integrate phase.

#define SYS_PER_BLK 64
#define ROW_F   308   // 100 pts * 3 = 300 floats + 8 pad; 77 float4/row
#define ROW_F4  77    // 77 mod 8 = 5 -> ds_write banks spread across all 8 quad-groups

__global__ __launch_bounds__(64) void sir_rk4_kernel(
    const float* __restrict__ params, float* __restrict__ out)
{
    const int t  = threadIdx.x;
    const int b0 = blockIdx.x * SYS_PER_BLK;
    const int b  = b0 + t;

    __shared__ float lbuf[SYS_PER_BLK * ROW_F];

    const float4 p = reinterpret_cast<const float4*>(params)[b];
    const float beta = p.x, gamma = p.y;
    float S = p.z, I = p.w;
    float R = 1.0f - S - I;

    const float dt = 100.0f / 199.0f;
    const float h2 = 0.5f * dt;
    const float h6 = dt / 6.0f;

    auto step = [&]() {
        float bSI1 = beta * S * I;
        float gI1  = gamma * I;
        float k1S = -bSI1, k1I = bSI1 - gI1, k1R = gI1;
        float S2 = __builtin_fmaf(h2, k1S, S);
        float I2 = __builtin_fmaf(h2, k1I, I);
        float bSI2 = beta * S2 * I2;
        float gI2  = gamma * I2;
        float k2S = -bSI2, k2I = bSI2 - gI2, k2R = gI2;
        float S3 = __builtin_fmaf(h2, k2S, S);
        float I3 = __builtin_fmaf(h2, k2I, I);
        float bSI3 = beta * S3 * I3;
        float gI3  = gamma * I3;
        float k3S = -bSI3, k3I = bSI3 - gI3, k3R = gI3;
        float S4 = __builtin_fmaf(dt, k3S, S);
        float I4 = __builtin_fmaf(dt, k3I, I);
        float bSI4 = beta * S4 * I4;
        float gI4  = gamma * I4;
        float k4S = -bSI4, k4I = bSI4 - gI4, k4R = gI4;
        S = __builtin_fmaf(h6, k1S + 2.0f * (k2S + k3S) + k4S, S);
        I = __builtin_fmaf(h6, k1I + 2.0f * (k2I + k3I) + k4I, I);
        R = __builtin_fmaf(h6, k1R + 2.0f * (k2R + k3R) + k4R, R);
    };

    float4* lrow = reinterpret_cast<float4*>(&lbuf[t * ROW_F]);
    float4* gout = reinterpret_cast<float4*>(out) + (size_t)b0 * 150;  // 600 f/row

    for (int c = 0; c < 2; ++c) {
        // integrate 100 points (25 groups of 4) into this thread's LDS row
        #pragma unroll 5
        for (int g = 0; g < 25; ++g) {
            float4 va, vb, vc;
            if (c == 0 && g == 0) { va.x = S; va.y = I; va.z = R; }
            else                  { step(); va.x = S; va.y = I; va.z = R; }
            step(); va.w = S; vb.x = I; vb.y = R;
            step(); vb.z = S; vb.w = I; vc.x = R;
            step(); vc.y = S; vc.z = I; vc.w = R;
            lrow[g * 3 + 0] = va;
            lrow[g * 3 + 1] = vb;
            lrow[g * 3 + 2] = vc;
        }
        // barrier-free coalesced flush: 64 rows x 75 float4 (1200 B runs).
        // Single-wave block: DS in-order + compiler lgkmcnt ordering make the
        // transpose safe; WAR (next integrate overwriting) is also ordered.
        #pragma unroll 5
        for (int it = 0; it < 75; ++it) {
            int f = it * 64 + t;
            int r = f / 75;
            int q = f - r * 75;
            float4 v = *reinterpret_cast<const float4*>(&lbuf[r * ROW_F + q * 4]);
            gout[(size_t)r * 150 + c * 75 + q] = v;
        }
    }
}

extern "C" void kernel_launch(void* const* d_in, const int* in_sizes, int n_in,
                              void* d_out, int out_size, void* d_ws, size_t ws_size,
                              hipStream_t stream) {
    const float* params = (const float*)d_in[0];
    float* out = (float*)d_out;
    const int B = in_sizes[0] / 4;                 // 65536
    const int grid = B / SYS_PER_BLK;              // 1024 blocks
    sir_rk4_kernel<<<grid, SYS_PER_BLK, 0, stream>>>(params, out);
}

// Round 5
// 37.854 us; speedup vs baseline: 1.4677x; 1.4677x over previous
//
#include <hip/hip_runtime.h>

// SIR RK4, B=65536, 200 points, out (B,200,3) f32 = 157.3 MB.
// Round 5: smooth store issue. Double-buffered 20-point chunks; while
// integrating chunk c (5 groups of 4 steps), issue 3 coalesced float4 store
// insts of chunk c-1 per group (15 insts/chunk). Store issue duty cycle goes
// from bursty (R2) to ~continuous. 64 systems/block, 1 wave, barrier-free,
// LDS 2x15KB=30KB -> 4 blocks/CU.

#define SYS 64
#define NCH 10
#define CF4 15          // float4 per row per chunk (20 pts * 3 / 4)
#define ROW_F 60        // floats per row in chunk buffer
#define BUF_F (SYS * ROW_F)

__global__ __launch_bounds__(64) void sir_rk4_kernel(
    const float* __restrict__ params, float* __restrict__ out)
{
    const int t  = threadIdx.x;
    const int b0 = blockIdx.x * SYS;

    __shared__ float lbuf[2 * BUF_F];

    const float4 p = reinterpret_cast<const float4*>(params)[b0 + t];
    const float beta = p.x, gamma = p.y;
    float S = p.z, I = p.w;
    float R = 1.0f - S - I;

    const float dt = 100.0f / 199.0f;
    const float h2 = 0.5f * dt;
    const float h6 = dt / 6.0f;

    auto step = [&]() {
        float bSI1 = beta * S * I;
        float gI1  = gamma * I;
        float k1S = -bSI1, k1I = bSI1 - gI1, k1R = gI1;
        float S2 = __builtin_fmaf(h2, k1S, S);
        float I2 = __builtin_fmaf(h2, k1I, I);
        float bSI2 = beta * S2 * I2;
        float gI2  = gamma * I2;
        float k2S = -bSI2, k2I = bSI2 - gI2, k2R = gI2;
        float S3 = __builtin_fmaf(h2, k2S, S);
        float I3 = __builtin_fmaf(h2, k2I, I);
        float bSI3 = beta * S3 * I3;
        float gI3  = gamma * I3;
        float k3S = -bSI3, k3I = bSI3 - gI3, k3R = gI3;
        float S4 = __builtin_fmaf(dt, k3S, S);
        float I4 = __builtin_fmaf(dt, k3I, I);
        float bSI4 = beta * S4 * I4;
        float gI4  = gamma * I4;
        float k4S = -bSI4, k4I = bSI4 - gI4, k4R = gI4;
        S = __builtin_fmaf(h6, k1S + 2.0f * (k2S + k3S) + k4S, S);
        I = __builtin_fmaf(h6, k1I + 2.0f * (k2I + k3I) + k4I, I);
        R = __builtin_fmaf(h6, k1R + 2.0f * (k2R + k3R) + k4R, R);
    };

    float4* gout = reinterpret_cast<float4*>(out) + (size_t)b0 * 150;

    // ---- chunk 0 into buffer 0 (no flush yet) ----
    {
        float4* lrow = reinterpret_cast<float4*>(&lbuf[t * ROW_F]);
        float4 va, vb, vc;
        va.x = S; va.y = I; va.z = R;          // point 0 = initial state
        step(); va.w = S; vb.x = I; vb.y = R;
        step(); vb.z = S; vb.w = I; vc.x = R;
        step(); vc.y = S; vc.z = I; vc.w = R;
        lrow[0] = va; lrow[1] = vb; lrow[2] = vc;
        #pragma unroll
        for (int g = 1; g < 5; ++g) {
            step(); va.x = S; va.y = I; va.z = R;
            step(); va.w = S; vb.x = I; vb.y = R;
            step(); vb.z = S; vb.w = I; vc.x = R;
            step(); vc.y = S; vc.z = I; vc.w = R;
            lrow[g * 3 + 0] = va; lrow[g * 3 + 1] = vb; lrow[g * 3 + 2] = vc;
        }
    }

    // ---- chunks 1..9: integrate chunk c, flush chunk c-1 interleaved ----
    for (int c = 1; c < NCH; ++c) {
        const int curo  = (c & 1) * BUF_F;
        const int prevo = BUF_F - curo;
        const int coff  = (c - 1) * CF4;       // chunk c-1's float4 offset in row
        #pragma unroll
        for (int g = 0; g < 5; ++g) {
            float4 va, vb, vc;
            step(); va.x = S; va.y = I; va.z = R;
            step(); va.w = S; vb.x = I; vb.y = R;
            step(); vb.z = S; vb.w = I; vc.x = R;
            step(); vc.y = S; vc.z = I; vc.w = R;
            float4* lrow = reinterpret_cast<float4*>(&lbuf[curo + t * ROW_F]) + g * 3;
            lrow[0] = va; lrow[1] = vb; lrow[2] = vc;
            // flush 3 store-insts of chunk c-1 (rows row-major, 240 B runs)
            #pragma unroll
            for (int jj = 0; jj < 3; ++jj) {
                int f = (g * 3 + jj) * 64 + t;
                int r = f / CF4;
                int q = f - r * CF4;
                float4 v = *reinterpret_cast<const float4*>(&lbuf[prevo + r * ROW_F + q * 4]);
                gout[(size_t)r * 150 + coff + q] = v;
            }
        }
    }

    // ---- tail: flush chunk 9 (buffer offset BUF_F since 9 is odd) ----
    #pragma unroll
    for (int j = 0; j < CF4; ++j) {
        int f = j * 64 + t;
        int r = f / CF4;
        int q = f - r * CF4;
        float4 v = *reinterpret_cast<const float4*>(&lbuf[BUF_F + r * ROW_F + q * 4]);
        gout[(size_t)r * 150 + 9 * CF4 + q] = v;
    }
}

extern "C" void kernel_launch(void* const* d_in, const int* in_sizes, int n_in,
                              void* d_out, int out_size, void* d_ws, size_t ws_size,
                              hipStream_t stream) {
    const float* params = (const float*)d_in[0];
    float* out = (float*)d_out;
    const int B = in_sizes[0] / 4;           // 65536
    const int grid = B / SYS;                // 1024 blocks
    sir_rk4_kernel<<<grid, SYS, 0, stream>>>(params, out);
}